// Round 3
// baseline (6688.263 us; speedup 1.0000x reference)
//
#include <hip/hip_runtime.h>

// Problem constants
#define NB 256   // batch
#define TT 256   // time steps
#define II 512   // input dim
#define HH 512   // hidden dim
#define GG 1536  // 3*H gates

typedef unsigned short ushort_t;
typedef unsigned int uint_t;
typedef __attribute__((ext_vector_type(8))) short short8;   // 8 x bf16 (4 VGPRs)
typedef __attribute__((ext_vector_type(4))) float f32x4;    // MFMA accumulator

__device__ __forceinline__ ushort_t f2bf(float f) {
  union { float f; unsigned int u; } x; x.f = f;
  unsigned int r = x.u + 0x7FFFu + ((x.u >> 16) & 1u);  // RNE
  return (ushort_t)(r >> 16);
}
__device__ __forceinline__ float bf2f(ushort_t b) {
  union { unsigned int u; float f; } x; x.u = ((unsigned int)b) << 16;
  return x.f;
}
__device__ __forceinline__ float sigmoidf_(float x) {
  return __fdividef(1.0f, 1.0f + __expf(-x));
}
__device__ __forceinline__ float tanhf_(float x) {
  float t = __expf(2.0f * x);
  return 1.0f - __fdividef(2.0f, t + 1.0f);
}
__device__ __forceinline__ short8 pack8(float4 a, float4 b) {
  short8 r;
  r[0] = (short)f2bf(a.x); r[1] = (short)f2bf(a.y);
  r[2] = (short)f2bf(a.z); r[3] = (short)f2bf(a.w);
  r[4] = (short)f2bf(b.x); r[5] = (short)f2bf(b.y);
  r[6] = (short)f2bf(b.z); r[7] = (short)f2bf(b.w);
  return r;
}

// ---------------------------------------------------------------------------
// is_init canonicalization -> uint8 mask. Handles uint8 / int32 / float32 /
// int64 storage of the bool [N,T] array (harness passes "integer -> int*",
// so int32 expected; keep the robust detector anyway).
__global__ void mask_detect_kernel(const unsigned char* __restrict__ src,
                                   unsigned char* __restrict__ mask8) {
  __shared__ int fByte, fOdd;
  const int tid = threadIdx.x;
  if (tid == 0) { fByte = 0; fOdd = 0; }
  __syncthreads();
  const uint_t* w = (const uint_t*)src;
  int ab = 0, ao = 0;
  for (int i = tid; i < NB * TT; i += blockDim.x) {
    if ((i & 3) == 1 && src[i]) ab = 1;                 // only uint8 layout hits
    if (i < 16384 && (i & 1) == 1 && w[i]) ao = 1;      // odd words: 32-bit layouts
  }
  if (ab) fByte = 1;
  if (ao) fOdd = 1;
  __syncthreads();
  const int isByte = fByte, isW32 = fOdd;
  for (int i = tid; i < NB * TT; i += blockDim.x) {
    unsigned char m;
    if (isByte)      m = src[i] ? 1 : 0;
    else if (isW32)  m = w[i] ? 1 : 0;        // int32 or float32
    else             m = w[2 * i] ? 1 : 0;    // int64 low word
    mask8[i] = m;
  }
}

// ---------------------------------------------------------------------------
// f32 -> bf16 vectorized convert (n4 = n/4 float4 chunks)
__global__ void cvt_f2bf(const float* __restrict__ src, ushort_t* __restrict__ dst,
                         int n4) {
  int stride = gridDim.x * blockDim.x;
  for (int i = blockIdx.x * blockDim.x + threadIdx.x; i < n4; i += stride) {
    const float4 v = reinterpret_cast<const float4*>(src)[i];
    ushort4 o;
    o.x = f2bf(v.x); o.y = f2bf(v.y); o.z = f2bf(v.z); o.w = f2bf(v.w);
    reinterpret_cast<ushort4*>(dst)[i] = o;
  }
}

// ---------------------------------------------------------------------------
// Pack W_hh [1536][512] f32 into MFMA-B-fragment order (bf16):
// Wpk[((tile*16+kk)*64 + lane)*8 + e] = W[tile*16 + (lane&15)][kk*32 + (lane>>4)*8 + e]
__global__ void pack_whh(const float* __restrict__ W, ushort_t* __restrict__ out) {
  int idx = blockIdx.x * blockDim.x + threadIdx.x;  // 96*16*64 = 98304
  if (idx >= 96 * 16 * 64) return;
  int l = idx & 63;
  int tk = idx >> 6;
  int tile = tk >> 4, kk = tk & 15;
  int row = tile * 16 + (l & 15);
  int k = kk * 32 + (l >> 4) * 8;
  const float* s = W + (size_t)row * HH + k;
  short8 v;
#pragma unroll
  for (int e = 0; e < 8; ++e) v[e] = (short)f2bf(s[e]);
  *reinterpret_cast<short8*>(out + (size_t)idx * 8) = v;
}

// ---------------------------------------------------------------------------
// GEMM: C[m][c] = sum_k A[m][k]*B[c][k] + bias[c].  B bf16 row-major K=512.
// A: f32 (AF32=1, converted during staging) or bf16 (AF32=0).
// C: f32 (CF32=1) or bf16 (CF32=0).
// 128x128 tile, 4 waves, reg-staged LDS with next-tile prefetch.
template <int AF32, int CF32>
__global__ __launch_bounds__(256) void gemm_bt(
    const void* __restrict__ Av, const ushort_t* __restrict__ B,
    const float* __restrict__ bias, void* __restrict__ Cv, int NC) {
  __shared__ ushort_t As[128 * 32];
  __shared__ ushort_t Bs[128 * 32];
  const int tid = threadIdx.x;
  const int lane = tid & 63;
  const int w = tid >> 6;
  const int wr = w >> 1, wc = w & 1;
  const int c15 = lane & 15, l4 = lane >> 4;
  const int mbase = blockIdx.x * 128;
  const int nbase = blockIdx.y * 128;

  const int rs = tid >> 2;            // staging row (0..63), +64 for chunk 1
  const int kb = (tid & 3) * 8;       // staging k-offset (0,8,16,24)

  f32x4 acc[4][4] = {};

  const float4* Bg = reinterpret_cast<const float4*>(B);
  auto bIdx = [&](int c, int kt) {
    return ((size_t)(nbase + rs + 64 * c) * 512 + kt * 32 + kb) >> 3;
  };
  float4 rb0 = Bg[bIdx(0, 0)], rb1 = Bg[bIdx(1, 0)];

  const float4* Agf = reinterpret_cast<const float4*>(Av);
  auto aEl = [&](int c, int kt) {  // element offset into A
    return (size_t)(mbase + rs + 64 * c) * 512 + kt * 32 + kb;
  };
  float4 a0a, a0b, a1a, a1b;   // f32 path regs
  float4 h0, h1;               // bf16 path regs (16B = 8 bf16)
  if constexpr (AF32) {
    a0a = Agf[aEl(0, 0) >> 2]; a0b = Agf[(aEl(0, 0) >> 2) + 1];
    a1a = Agf[aEl(1, 0) >> 2]; a1b = Agf[(aEl(1, 0) >> 2) + 1];
  } else {
    h0 = Agf[aEl(0, 0) >> 3];
    h1 = Agf[aEl(1, 0) >> 3];
  }

  for (int kt = 0; kt < 16; ++kt) {
    __syncthreads();  // previous compute done reading LDS
    if constexpr (AF32) {
      *reinterpret_cast<short8*>(&As[(size_t)tid * 8]) = pack8(a0a, a0b);
      *reinterpret_cast<short8*>(&As[(size_t)(tid + 256) * 8]) = pack8(a1a, a1b);
    } else {
      reinterpret_cast<float4*>(As)[tid] = h0;
      reinterpret_cast<float4*>(As)[tid + 256] = h1;
    }
    reinterpret_cast<float4*>(Bs)[tid] = rb0;
    reinterpret_cast<float4*>(Bs)[tid + 256] = rb1;
    if (kt < 15) {  // prefetch next tile; HBM latency overlaps compute below
      if constexpr (AF32) {
        a0a = Agf[aEl(0, kt + 1) >> 2]; a0b = Agf[(aEl(0, kt + 1) >> 2) + 1];
        a1a = Agf[aEl(1, kt + 1) >> 2]; a1b = Agf[(aEl(1, kt + 1) >> 2) + 1];
      } else {
        h0 = Agf[aEl(0, kt + 1) >> 3];
        h1 = Agf[aEl(1, kt + 1) >> 3];
      }
      rb0 = Bg[bIdx(0, kt + 1)]; rb1 = Bg[bIdx(1, kt + 1)];
    }
    __syncthreads();  // LDS visible
    short8 af[4], bq[4];
#pragma unroll
    for (int m = 0; m < 4; ++m)
      af[m] = *reinterpret_cast<const short8*>(&As[(wr * 64 + m * 16 + c15) * 32 + l4 * 8]);
#pragma unroll
    for (int n = 0; n < 4; ++n)
      bq[n] = *reinterpret_cast<const short8*>(&Bs[(wc * 64 + n * 16 + c15) * 32 + l4 * 8]);
#pragma unroll
    for (int m = 0; m < 4; ++m)
#pragma unroll
      for (int n = 0; n < 4; ++n)
        acc[m][n] = __builtin_amdgcn_mfma_f32_16x16x32_bf16(af[m], bq[n], acc[m][n], 0, 0, 0);
  }

  // epilogue: C/D layout col=lane&15, row=(lane>>4)*4+q  [m89-verified]
#pragma unroll
  for (int n = 0; n < 4; ++n) {
    const int col = nbase + wc * 64 + n * 16 + c15;
    const float bv = bias[col];
#pragma unroll
    for (int m = 0; m < 4; ++m) {
      const int row = mbase + wr * 64 + m * 16 + l4 * 4;
#pragma unroll
      for (int q = 0; q < 4; ++q) {
        const float v = acc[m][n][q] + bv;
        if constexpr (CF32)
          reinterpret_cast<float*>(Cv)[(size_t)(row + q) * NC + col] = v;
        else
          reinterpret_cast<ushort_t*>(Cv)[(size_t)(row + q) * NC + col] = f2bf(v);
      }
    }
  }
}

// ---------------------------------------------------------------------------
// GRU recurrence. 16 blocks x 512 threads (8 waves). Block owns 16 samples.
// hs written bf16 (feeds gemm3); hT written f32 (feeds hx_out broadcast).
__global__ __launch_bounds__(512) void gru_rec(
    const ushort_t* __restrict__ xi, const ushort_t* __restrict__ Wpk,
    const float* __restrict__ hx, const float* __restrict__ bhh,
    const unsigned char* __restrict__ mask8,
    ushort_t* __restrict__ hs, float* __restrict__ hT) {
  __shared__ float hF[16][512];        // f32 hidden state
  __shared__ ushort_t hB[16][520];     // bf16 copy for MFMA A-operand (padded)
  const int tid = threadIdx.x;
  const int lane = tid & 63;
  const int w = tid >> 6;              // wave 0..7 -> hidden slice w*64
  const int c15 = lane & 15, l4 = lane >> 4;
  const int n0 = blockIdx.x * 16;

  for (int i = tid; i < 16 * 512; i += 512) {
    int s = i >> 9, j = i & 511;
    hF[s][j] = hx[(size_t)(n0 + s) * TT * HH + j];  // hx[:,0,:]
  }

  const int sA = tid >> 5;             // phase-A sample (0..15)
  const int jA = tid & 31;
  const unsigned char* mrow = mask8 + (n0 + sA) * TT;

  int jj[4]; float br[4], bz[4], bn[4];
#pragma unroll
  for (int t4 = 0; t4 < 4; ++t4) {
    jj[t4] = w * 64 + t4 * 16 + c15;
    br[t4] = bhh[jj[t4]];
    bz[t4] = bhh[512 + jj[t4]];
    bn[t4] = bhh[1024 + jj[t4]];
  }
  __syncthreads();

  for (int t = 0; t < TT; ++t) {
    // phase A: per-step init mask + f32->bf16
    const bool mk = (mrow[t] != 0);
#pragma unroll
    for (int ii = 0; ii < 16; ++ii) {
      int j = jA + 32 * ii;
      float v = mk ? 0.0f : hF[sA][j];
      hF[sA][j] = v;
      hB[sA][j] = f2bf(v);
    }
    __syncthreads();

    // phase B: hh = h @ W_hh^T, wave w owns 12 tiles (3 gates x 4 subtiles)
    f32x4 acc[3][4] = {};
#pragma unroll 2
    for (int kk = 0; kk < 16; ++kk) {
      short8 a = *reinterpret_cast<const short8*>(&hB[c15][kk * 32 + l4 * 8]);
#pragma unroll
      for (int g = 0; g < 3; ++g)
#pragma unroll
        for (int t4 = 0; t4 < 4; ++t4) {
          const int tile = g * 32 + w * 4 + t4;
          short8 b = *reinterpret_cast<const short8*>(
              Wpk + (((size_t)tile * 16 + kk) * 64 + lane) * 8);
          acc[g][t4] = __builtin_amdgcn_mfma_f32_16x16x32_bf16(a, b, acc[g][t4], 0, 0, 0);
        }
    }

    // gates: n = tanh(xn + r*hn)  (hn includes b_hh_n, PyTorch semantics)
#pragma unroll
    for (int t4 = 0; t4 < 4; ++t4) {
      const int J = jj[t4];
#pragma unroll
      for (int q = 0; q < 4; ++q) {
        const int s = l4 * 4 + q;
        const size_t xib = ((size_t)(n0 + s) * TT + t) * GG;
        const float xr = bf2f(xi[xib + J]);
        const float xz = bf2f(xi[xib + 512 + J]);
        const float xn = bf2f(xi[xib + 1024 + J]);
        const float rr = sigmoidf_(xr + acc[0][t4][q] + br[t4]);
        const float zz = sigmoidf_(xz + acc[1][t4][q] + bz[t4]);
        const float nn = tanhf_(xn + rr * (acc[2][t4][q] + bn[t4]));
        const float hold = hF[s][J];
        const float hnew = (1.0f - zz) * nn + zz * hold;
        hF[s][J] = hnew;
        hs[((size_t)(n0 + s) * TT + t) * HH + J] = f2bf(hnew);
      }
    }
    __syncthreads();
  }

  // final h (f32) for the broadcast kernel; coalesced along tid
#pragma unroll
  for (int s = 0; s < 16; ++s)
    hT[(size_t)(n0 + s) * HH + tid] = hF[s][tid];
}

// ---------------------------------------------------------------------------
// hx_out[n,t,:] = hT[n,:]  (f32, overwrites the hs scratch region after gemm3)
__global__ void bcast_hT(const float* __restrict__ hT, float* __restrict__ dst) {
  const float4* s = (const float4*)hT;
  float4* d = (float4*)dst;
  const int total = NB * TT * HH / 4;  // 8,388,608 chunks
  const int stride = gridDim.x * blockDim.x;
  for (int c = blockIdx.x * blockDim.x + threadIdx.x; c < total; c += stride) {
    int n = c >> 15;        // TT*HH/4 = 32768 chunks per sample
    int j4 = c & 127;       // HH/4 = 128 chunks per row
    d[c] = s[(n << 7) | j4];
  }
}

// ---------------------------------------------------------------------------
extern "C" void kernel_launch(void* const* d_in, const int* in_sizes, int n_in,
                              void* d_out, int out_size, void* d_ws, size_t ws_size,
                              hipStream_t stream) {
  const float* x    = (const float*)d_in[0];
  const float* hx   = (const float*)d_in[1];
  const float* Wih  = (const float*)d_in[2];
  const float* Whh  = (const float*)d_in[3];
  const float* bih  = (const float*)d_in[4];
  const float* bhh  = (const float*)d_in[5];
  const float* Wout = (const float*)d_in[6];
  const float* bout = (const float*)d_in[7];
  const unsigned char* isinit = (const unsigned char*)d_in[8];

  // Workspace layout (~196 MiB total):
  //   xi    bf16 [65536][1536] @ 0           (201,326,592 B)
  //   wihb  bf16 [1536][512]   @ 201,326,592 (1,572,864 B)
  //   whhp  packed bf16        @ 202,899,456 (1,572,864 B)
  //   woutb bf16 [512][512]    @ 204,472,320 (524,288 B)
  //   mask8 u8   [65536]       @ 204,996,608 (65,536 B)
  //   hTbuf f32  [256][512]    @ 205,062,144 (524,288 B)
  char* ws = (char*)d_ws;
  ushort_t* xi    = (ushort_t*)(ws);
  ushort_t* wihb  = (ushort_t*)(ws + 201326592);
  ushort_t* whhp  = (ushort_t*)(ws + 202899456);
  ushort_t* woutb = (ushort_t*)(ws + 204472320);
  unsigned char* mask8 = (unsigned char*)(ws + 204996608);
  float*    hTbuf = (float*)(ws + 205062144);

  // d_out is FLOAT32 (reference outputs f32): output then hx_out, each [N,T,H]
  float* out1 = (float*)d_out;                       // output [N,T,H] f32
  float* out2 = out1 + (size_t)NB * TT * HH;         // hx_out [N,T,H] f32
  // hs (bf16, 67 MB) lives in the out2 region (134 MB) until bcast overwrites
  ushort_t* hsb = (ushort_t*)out2;

  mask_detect_kernel<<<1, 1024, 0, stream>>>(isinit, mask8);
  cvt_f2bf<<<768, 256, 0, stream>>>(Wih, wihb, GG * II / 4);
  cvt_f2bf<<<256, 256, 0, stream>>>(Wout, woutb, HH * HH / 4);
  pack_whh<<<384, 256, 0, stream>>>(Whh, whhp);

  dim3 g1(512, 12);  // M/128 x 3H/128
  gemm_bt<1, 0><<<g1, 256, 0, stream>>>((const void*)x, wihb, bih, (void*)xi, GG);

  gru_rec<<<16, 512, 0, stream>>>(xi, whhp, hx, bhh, mask8, hsb, hTbuf);

  dim3 g3(512, 4);   // M/128 x H/128
  gemm_bt<0, 1><<<g3, 256, 0, stream>>>((const void*)hsb, woutb, bout, (void*)out1, HH);

  bcast_hT<<<2048, 256, 0, stream>>>(hTbuf, out2);
}